// Round 1
// baseline (184.013 us; speedup 1.0000x reference)
//
#include <hip/hip_runtime.h>
#include <hip/hip_bf16.h>
#include <stdint.h>

#define T_TOK 4096
#define DIM   1024
#define NE    16
#define NDFF  1024
#define CAPN  512

typedef unsigned int   u32;
typedef unsigned short u16;
typedef __attribute__((ext_vector_type(8))) short bf16x8;
typedef __attribute__((ext_vector_type(4))) float f32x4;

// ---------- helpers ----------
__device__ __forceinline__ void gll16(void* lds, const void* g) {
  // union trick to get addrspace(1)/(3) pointers without illegal casts.
  union { const void* p; const __attribute__((address_space(1))) void* q; } gu;
  union { void* p; __attribute__((address_space(3))) void* q; } lu;
  gu.p = g; lu.p = lds;
  __builtin_amdgcn_global_load_lds(gu.q, lu.q, 16, 0, 0);
}

__device__ __forceinline__ u16 f2bf(float f) {
  u32 u = __float_as_uint(f);
  u32 r = (u + 0x7FFFu + ((u >> 16) & 1u)) >> 16;   // RNE
  return (u16)r;
}

__device__ __forceinline__ float gelu_tanh(float x) {
  float x3 = x * x * x;
  float z = 0.7978845608028654f * (x + 0.044715f * x3);
  return 0.5f * x * (1.0f + tanhf(z));
}

// ---------- K1: router (f32 exact) ----------
__global__ __launch_bounds__(64) void router_kernel(
    const float* __restrict__ h, const float* __restrict__ Wr,
    float* __restrict__ logits, u32* __restrict__ topmask, u32* __restrict__ keptmask)
{
  const int t = blockIdx.x;
  const int lane = threadIdx.x;
  float acc[NE];
#pragma unroll
  for (int e = 0; e < NE; ++e) acc[e] = 0.f;
  const float* hrow = h + (size_t)t * DIM;
#pragma unroll 4
  for (int i = 0; i < DIM / 64; ++i) {
    int d = lane + 64 * i;
    float hv = hrow[d];
    const float4* wr4 = (const float4*)(Wr + (size_t)d * NE);
#pragma unroll
    for (int q = 0; q < 4; ++q) {
      float4 w = wr4[q];
      acc[q*4+0] += hv * w.x; acc[q*4+1] += hv * w.y;
      acc[q*4+2] += hv * w.z; acc[q*4+3] += hv * w.w;
    }
  }
#pragma unroll
  for (int e = 0; e < NE; ++e) {
    float v = acc[e];
#pragma unroll
    for (int off = 32; off; off >>= 1) v += __shfl_xor(v, off);
    acc[e] = v;
  }
  int m1 = 0; float b1 = acc[0];
#pragma unroll
  for (int e = 1; e < NE; ++e) if (acc[e] > b1) { b1 = acc[e]; m1 = e; }
  int m2 = 0; float b2 = -3.4e38f;
#pragma unroll
  for (int e = 0; e < NE; ++e) if (e != m1 && acc[e] > b2) { b2 = acc[e]; m2 = e; }
  if (lane < NE) logits[(size_t)t * NE + lane] = acc[lane];
  if (lane == 0) { topmask[t] = (1u << m1) | (1u << m2); keptmask[t] = 0u; }
}

// ---------- K2: per-expert capacity selection (exact, tie=lower index) ----------
__global__ __launch_bounds__(1024) void capacity_kernel(
    const float* __restrict__ logits, const u32* __restrict__ topmask,
    u32* __restrict__ keptmask, int* __restrict__ expert_tokens)
{
  const int e = blockIdx.x;
  const int tid = threadIdx.x;
  const int lane = tid & 63, wv = tid >> 6;
  __shared__ u32 wred[16];
  __shared__ u32 wscan[16];
  __shared__ u32 bcast;

  u32 key[4];
#pragma unroll
  for (int j = 0; j < 4; ++j) {
    int t = tid * 4 + j;
    float lg = logits[(size_t)t * NE + e];
    u32 u = __float_as_uint(lg);
    u32 ord = (u >> 31) ? ~u : (u | 0x80000000u);   // order-preserving map
    bool sel = (topmask[t] >> e) & 1u;
    key[j] = sel ? ord : 0u;                        // 0 == "not selected"
  }

  auto blockReduce = [&](u32 v) -> u32 {
#pragma unroll
    for (int off = 32; off; off >>= 1) v += __shfl_xor(v, off);
    if (lane == 0) wred[wv] = v;
    __syncthreads();
    if (tid == 0) { u32 s = 0; for (int i = 0; i < 16; ++i) s += wred[i]; bcast = s; }
    __syncthreads();
    u32 r = bcast;
    __syncthreads();
    return r;
  };

  u32 nsel = blockReduce((key[0] != 0u) + (key[1] != 0u) + (key[2] != 0u) + (key[3] != 0u));

  u32 p = 0, need = 0;
  if (nsel > CAPN) {
    need = CAPN;
    for (int b = 31; b >= 0; --b) {
      u32 cand = p | (1u << b);
      u32 hi = ~((1u << b) - 1u);
      u32 loc = 0;
#pragma unroll
      for (int j = 0; j < 4; ++j) loc += ((key[j] & hi) == cand) ? 1u : 0u;
      u32 c = blockReduce(loc);
      if (c >= need) p = cand; else need -= c;
    }
  }

  auto blockExScan = [&](u32 v, u32& total) -> u32 {
    u32 x = v;
#pragma unroll
    for (int off = 1; off < 64; off <<= 1) { u32 y = __shfl_up(x, off); if (lane >= off) x += y; }
    if (lane == 63) wscan[wv] = x;
    __syncthreads();
    if (wv == 0) {
      u32 w = (lane < 16) ? wscan[lane] : 0u;
#pragma unroll
      for (int off = 1; off < 16; off <<= 1) { u32 y = __shfl_up(w, off); if (lane >= off) w += y; }
      if (lane < 16) wscan[lane] = w;
    }
    __syncthreads();
    u32 base = wv ? wscan[wv - 1] : 0u;
    total = wscan[15];
    __syncthreads();
    return base + x - v;
  };

  bool eq[4], kept[4];
  u32 eqc = 0;
#pragma unroll
  for (int j = 0; j < 4; ++j) { eq[j] = (key[j] != 0u) && (key[j] == p); eqc += eq[j] ? 1u : 0u; }
  u32 eqtot;
  u32 eqbase = blockExScan(eqc, eqtot);
  u32 keptc = 0;
  {
    u32 er = eqbase;
#pragma unroll
    for (int j = 0; j < 4; ++j) {
      kept[j] = (key[j] != 0u) && ((key[j] > p) || (eq[j] && er < need));
      er += eq[j] ? 1u : 0u;
      keptc += kept[j] ? 1u : 0u;
    }
  }
  u32 ktot;
  u32 kbase = blockExScan(keptc, ktot);
  {
    u32 slot = kbase;
#pragma unroll
    for (int j = 0; j < 4; ++j) {
      if (kept[j]) {
        int t = tid * 4 + j;
        expert_tokens[e * CAPN + slot] = t;
        atomicOr(&keptmask[t], 1u << e);
        slot++;
      }
    }
  }
  for (u32 i = ktot + tid; i < CAPN; i += 1024) expert_tokens[e * CAPN + i] = -1;
}

// ---------- K3: rho + residual-rescale init of out ----------
__global__ __launch_bounds__(256) void rho_init_kernel(
    const float* __restrict__ h, const float* __restrict__ logits,
    const u32* __restrict__ keptmask, float* __restrict__ out)
{
  const int t = blockIdx.x;
  const int tid = threadIdx.x;
  float v[NE]; float m = -3.4e38f;
#pragma unroll
  for (int i = 0; i < NE; ++i) { v[i] = logits[(size_t)t * NE + i]; m = fmaxf(m, v[i]); }
  float sum = 0.f;
#pragma unroll
  for (int i = 0; i < NE; ++i) { v[i] = expf(v[i] - m); sum += v[i]; }
  u32 km = keptmask[t];
  float rho = 0.f;
#pragma unroll
  for (int i = 0; i < NE; ++i) if ((km >> i) & 1u) rho += v[i];
  rho /= sum;
  float s = 1.0f - rho;
  const float4 hv = *(const float4*)(h + (size_t)t * DIM + tid * 4);
  float4 o; o.x = hv.x * s; o.y = hv.y * s; o.z = hv.z * s; o.w = hv.w * s;
  *(float4*)(out + (size_t)t * DIM + tid * 4) = o;
}

// ---------- K4: transpose + f32->bf16 convert of weights ----------
__global__ __launch_bounds__(256) void transpose_convert(
    const float* __restrict__ W1, const float* __restrict__ W2,
    u16* __restrict__ W1t, u16* __restrict__ W2t)
{
  const int z = blockIdx.z;
  const float* in; u16* outp;
  if (z < NE) { in = W1 + (size_t)z * DIM * NDFF;        outp = W1t + (size_t)z * DIM * NDFF; }
  else        { in = W2 + (size_t)(z - NE) * NDFF * DIM; outp = W2t + (size_t)(z - NE) * NDFF * DIM; }
  __shared__ float tile[64][65];
  const int r0 = blockIdx.y * 64, c0 = blockIdx.x * 64;
  const int tx = threadIdx.x, ty = threadIdx.y;
#pragma unroll
  for (int i = 0; i < 16; ++i) { int r = i * 4 + ty; tile[r][tx] = in[(size_t)(r0 + r) * 1024 + c0 + tx]; }
  __syncthreads();
#pragma unroll
  for (int i = 0; i < 16; ++i) { int rr = i * 4 + ty; outp[(size_t)(c0 + rr) * 1024 + r0 + tx] = f2bf(tile[tx][rr]); }
}

// ---------- K5: gather kept token rows -> bf16 ----------
__global__ __launch_bounds__(64) void gather_kernel(
    const float* __restrict__ h, const int* __restrict__ expert_tokens, u16* __restrict__ Xg)
{
  const int slot = blockIdx.x;
  const int lane = threadIdx.x;
  const int t = expert_tokens[slot];
  u16* dst = Xg + (size_t)slot * DIM + lane * 16;
  if (t < 0) {
    uint4 z = make_uint4(0, 0, 0, 0);
    *(uint4*)dst = z; *(uint4*)(dst + 8) = z;
  } else {
    const float4* src = (const float4*)(h + (size_t)t * DIM + lane * 16);
    __align__(16) u16 tmp[16];
#pragma unroll
    for (int q = 0; q < 4; ++q) {
      float4 x = src[q];
      tmp[q*4+0] = f2bf(x.x); tmp[q*4+1] = f2bf(x.y);
      tmp[q*4+2] = f2bf(x.z); tmp[q*4+3] = f2bf(x.w);
    }
    *(uint4*)dst = *(const uint4*)tmp;
    *(uint4*)(dst + 8) = *(const uint4*)(tmp + 8);
  }
}

// ---------- K6: per-slot combine weights ----------
__global__ __launch_bounds__(256) void wts_kernel(
    const float* __restrict__ logits, const int* __restrict__ expert_tokens, float* __restrict__ w_ec)
{
  int s = blockIdx.x * 256 + threadIdx.x;
  if (s >= NE * CAPN) return;
  int t = expert_tokens[s];
  float w = 0.f;
  if (t >= 0) {
    int e = s / CAPN;
    float v[NE], m = -3.4e38f;
#pragma unroll
    for (int i = 0; i < NE; ++i) { v[i] = logits[(size_t)t * NE + i]; m = fmaxf(m, v[i]); }
    float sum = 0.f;
#pragma unroll
    for (int i = 0; i < NE; ++i) { v[i] = expf(v[i] - m); sum += v[i]; }
    w = v[e] / sum;
  }
  w_ec[s] = w;
}

// ---------- K7/K8: bf16 MFMA GEMM, A[M,K] x Bt[N,K]^T, 128x128 tile, BK=64 ----------
// EPI==1: gelu -> bf16 Hout.  EPI==2: out[token] += w * acc (atomic).
template <int EPI>
__global__ __launch_bounds__(256) void gemm_bt_kernel(
    const u16* __restrict__ Abase, const u16* __restrict__ Bbase,
    u16* __restrict__ Hout, float* __restrict__ out,
    const int* __restrict__ expert_tokens, const float* __restrict__ w_ec)
{
  const int e  = blockIdx.z;
  const int n0 = blockIdx.x * 128;
  const int m0 = blockIdx.y * 128;
  const char* A = (const char*)(Abase + (size_t)e * 512 * 1024);
  const char* B = (const char*)(Bbase + (size_t)e * 1024 * 1024);
  __shared__ __align__(16) u16 As[128 * 64];
  __shared__ __align__(16) u16 Bs[128 * 64];
  const int tid = threadIdx.x;
  const int lane = tid & 63, wave = tid >> 6;
  const int wr = wave >> 1, wc = wave & 1;
  f32x4 acc[4][4];
#pragma unroll
  for (int i = 0; i < 4; ++i)
#pragma unroll
    for (int j = 0; j < 4; ++j) acc[i][j] = (f32x4){0.f, 0.f, 0.f, 0.f};

  const int srow  = lane >> 3;                    // row within 8-row chunk
  const int sbyte = 16 * ((lane & 7) ^ srow);     // source-side XOR swizzle (rule #21)

  for (int kt = 0; kt < 16; ++kt) {
    const int kb0 = kt * 128;                     // 64 bf16 = 128 B per K-step
#pragma unroll
    for (int i = 0; i < 4; ++i) {
      const int c = wave * 4 + i;
      const int r = c * 8 + srow;
      gll16((char*)As + c * 1024, A + (size_t)(m0 + r) * 2048 + kb0 + sbyte);
      gll16((char*)Bs + c * 1024, B + (size_t)(n0 + r) * 2048 + kb0 + sbyte);
    }
    __syncthreads();
#pragma unroll
    for (int s = 0; s < 2; ++s) {
      bf16x8 af[4], bfv[4];
#pragma unroll
      for (int i = 0; i < 4; ++i) {
        const int rowa = wr * 64 + i * 16 + (lane & 15);
        const int rowb = wc * 64 + i * 16 + (lane & 15);
        const int kb = (s * 64 + (lane >> 4) * 16) ^ ((lane & 7) << 4);  // swizzled read
        af[i]  = *(const bf16x8*)((const char*)As + rowa * 128 + kb);
        bfv[i] = *(const bf16x8*)((const char*)Bs + rowb * 128 + kb);
      }
#pragma unroll
      for (int i = 0; i < 4; ++i)
#pragma unroll
        for (int j = 0; j < 4; ++j)
          acc[i][j] = __builtin_amdgcn_mfma_f32_16x16x32_bf16(af[i], bfv[j], acc[i][j], 0, 0, 0);
    }
    __syncthreads();
  }

  if (EPI == 1) {
#pragma unroll
    for (int i = 0; i < 4; ++i) {
#pragma unroll
      for (int r = 0; r < 4; ++r) {
        const int row = m0 + wr * 64 + i * 16 + (lane >> 4) * 4 + r;
        u16* hp = Hout + ((size_t)e * 512 + row) * 1024 + n0 + wc * 64 + (lane & 15);
#pragma unroll
        for (int j = 0; j < 4; ++j) hp[j * 16] = f2bf(gelu_tanh(acc[i][j][r]));
      }
    }
  } else {
#pragma unroll
    for (int i = 0; i < 4; ++i) {
#pragma unroll
      for (int r = 0; r < 4; ++r) {
        const int row  = m0 + wr * 64 + i * 16 + (lane >> 4) * 4 + r;
        const int slot = e * CAPN + row;
        const int t = expert_tokens[slot];
        if (t >= 0) {
          const float w = w_ec[slot];
          float* op = out + (size_t)t * DIM + n0 + wc * 64 + (lane & 15);
#pragma unroll
          for (int j = 0; j < 4; ++j) atomicAdd(op + j * 16, acc[i][j][r] * w);
        }
      }
    }
  }
}

// ---------- launch ----------
extern "C" void kernel_launch(void* const* d_in, const int* in_sizes, int n_in,
                              void* d_out, int out_size, void* d_ws, size_t ws_size,
                              hipStream_t stream)
{
  const float* h  = (const float*)d_in[0];
  const float* Wr = (const float*)d_in[1];
  const float* W1 = (const float*)d_in[2];
  const float* W2 = (const float*)d_in[3];
  float* out = (float*)d_out;

  char* ws = (char*)d_ws;
  u16* W1t = (u16*)(ws);                        // 33554432 B
  u16* W2t = (u16*)(ws + 33554432);             // 33554432 B
  u16* Xg  = (u16*)(ws + 67108864);             // 16777216 B
  u16* Hb  = (u16*)(ws + 83886080);             // 16777216 B
  float* logits       = (float*)(ws + 100663296); // 262144 B
  u32*   topmask      = (u32*)  (ws + 100925440); // 16384 B
  u32*   keptmask     = (u32*)  (ws + 100941824); // 16384 B
  int*   expert_tokens= (int*)  (ws + 100958208); // 32768 B
  float* w_ec         = (float*)(ws + 100990976); // 32768 B  (total ~96.4 MiB)

  router_kernel<<<T_TOK, 64, 0, stream>>>(h, Wr, logits, topmask, keptmask);
  capacity_kernel<<<NE, 1024, 0, stream>>>(logits, topmask, keptmask, expert_tokens);
  rho_init_kernel<<<T_TOK, 256, 0, stream>>>(h, logits, keptmask, out);
  transpose_convert<<<dim3(16, 16, 2 * NE), dim3(64, 4), 0, stream>>>(W1, W2, W1t, W2t);
  gather_kernel<<<NE * CAPN, 64, 0, stream>>>(h, expert_tokens, Xg);
  wts_kernel<<<(NE * CAPN + 255) / 256, 256, 0, stream>>>(logits, expert_tokens, w_ec);
  gemm_bt_kernel<1><<<dim3(8, 4, NE), 256, 0, stream>>>(Xg, W1t, Hb, nullptr, nullptr, nullptr);
  gemm_bt_kernel<2><<<dim3(8, 4, NE), 256, 0, stream>>>(Hb, W2t, nullptr, out, expert_tokens, w_ec);
}

// Round 2
// 183.487 us; speedup vs baseline: 1.0029x; 1.0029x over previous
//
#include <hip/hip_runtime.h>
#include <hip/hip_bf16.h>
#include <stdint.h>

#define T_TOK 4096
#define DIM   1024
#define NE    16
#define NDFF  1024
#define CAPN  512

typedef unsigned int   u32;
typedef unsigned short u16;
typedef __attribute__((ext_vector_type(8))) short bf16x8;
typedef __attribute__((ext_vector_type(4))) float f32x4;

// ---------- helpers ----------
__device__ __forceinline__ void gll16(void* lds, const void* g) {
  union { const void* p; const __attribute__((address_space(1))) void* q; } gu;
  union { void* p; __attribute__((address_space(3))) void* q; } lu;
  gu.p = g; lu.p = lds;
  __builtin_amdgcn_global_load_lds(gu.q, lu.q, 16, 0, 0);
}

__device__ __forceinline__ u16 f2bf(float f) {
  u32 u = __float_as_uint(f);
  u32 r = (u + 0x7FFFu + ((u >> 16) & 1u)) >> 16;   // RNE
  return (u16)r;
}

__device__ __forceinline__ float gelu_tanh(float x) {
  float x3 = x * x * x;
  float z = 0.7978845608028654f * (x + 0.044715f * x3);
  return 0.5f * x * (1.0f + tanhf(z));
}

// ---------- K1: router (f32 exact) ----------
__global__ __launch_bounds__(64) void router_kernel(
    const float* __restrict__ h, const float* __restrict__ Wr,
    float* __restrict__ logits, u32* __restrict__ topmask, u32* __restrict__ keptmask)
{
  const int t = blockIdx.x;
  const int lane = threadIdx.x;
  float acc[NE];
#pragma unroll
  for (int e = 0; e < NE; ++e) acc[e] = 0.f;
  const float* hrow = h + (size_t)t * DIM;
#pragma unroll 4
  for (int i = 0; i < DIM / 64; ++i) {
    int d = lane + 64 * i;
    float hv = hrow[d];
    const float4* wr4 = (const float4*)(Wr + (size_t)d * NE);
#pragma unroll
    for (int q = 0; q < 4; ++q) {
      float4 w = wr4[q];
      acc[q*4+0] += hv * w.x; acc[q*4+1] += hv * w.y;
      acc[q*4+2] += hv * w.z; acc[q*4+3] += hv * w.w;
    }
  }
#pragma unroll
  for (int e = 0; e < NE; ++e) {
    float v = acc[e];
#pragma unroll
    for (int off = 32; off; off >>= 1) v += __shfl_xor(v, off);
    acc[e] = v;
  }
  int m1 = 0; float b1 = acc[0];
#pragma unroll
  for (int e = 1; e < NE; ++e) if (acc[e] > b1) { b1 = acc[e]; m1 = e; }
  int m2 = 0; float b2 = -3.4e38f;
#pragma unroll
  for (int e = 0; e < NE; ++e) if (e != m1 && acc[e] > b2) { b2 = acc[e]; m2 = e; }
  if (lane < NE) logits[(size_t)t * NE + lane] = acc[lane];
  if (lane == 0) { topmask[t] = (1u << m1) | (1u << m2); keptmask[t] = 0u; }
}

// ---------- K2: per-expert capacity selection (exact, tie=lower index) ----------
__global__ __launch_bounds__(1024) void capacity_kernel(
    const float* __restrict__ logits, const u32* __restrict__ topmask,
    u32* __restrict__ keptmask, int* __restrict__ expert_tokens)
{
  const int e = blockIdx.x;
  const int tid = threadIdx.x;
  const int lane = tid & 63, wv = tid >> 6;
  __shared__ u32 wred[16];
  __shared__ u32 wscan[16];
  __shared__ u32 bcast;

  u32 key[4];
#pragma unroll
  for (int j = 0; j < 4; ++j) {
    int t = tid * 4 + j;
    float lg = logits[(size_t)t * NE + e];
    u32 u = __float_as_uint(lg);
    u32 ord = (u >> 31) ? ~u : (u | 0x80000000u);   // order-preserving map
    bool sel = (topmask[t] >> e) & 1u;
    key[j] = sel ? ord : 0u;                        // 0 == "not selected"
  }

  auto blockReduce = [&](u32 v) -> u32 {
#pragma unroll
    for (int off = 32; off; off >>= 1) v += __shfl_xor(v, off);
    if (lane == 0) wred[wv] = v;
    __syncthreads();
    if (tid == 0) { u32 s = 0; for (int i = 0; i < 16; ++i) s += wred[i]; bcast = s; }
    __syncthreads();
    u32 r = bcast;
    __syncthreads();
    return r;
  };

  u32 nsel = blockReduce((key[0] != 0u) + (key[1] != 0u) + (key[2] != 0u) + (key[3] != 0u));

  u32 p = 0, need = 0;
  if (nsel > CAPN) {
    need = CAPN;
    for (int b = 31; b >= 0; --b) {
      u32 cand = p | (1u << b);
      u32 hi = ~((1u << b) - 1u);
      u32 loc = 0;
#pragma unroll
      for (int j = 0; j < 4; ++j) loc += ((key[j] & hi) == cand) ? 1u : 0u;
      u32 c = blockReduce(loc);
      if (c >= need) p = cand; else need -= c;
    }
  }

  auto blockExScan = [&](u32 v, u32& total) -> u32 {
    u32 x = v;
#pragma unroll
    for (int off = 1; off < 64; off <<= 1) { u32 y = __shfl_up(x, off); if (lane >= off) x += y; }
    if (lane == 63) wscan[wv] = x;
    __syncthreads();
    if (wv == 0) {
      u32 w = (lane < 16) ? wscan[lane] : 0u;
#pragma unroll
      for (int off = 1; off < 16; off <<= 1) { u32 y = __shfl_up(w, off); if (lane >= off) w += y; }
      if (lane < 16) wscan[lane] = w;
    }
    __syncthreads();
    u32 base = wv ? wscan[wv - 1] : 0u;
    total = wscan[15];
    __syncthreads();
    return base + x - v;
  };

  bool eq[4], kept[4];
  u32 eqc = 0;
#pragma unroll
  for (int j = 0; j < 4; ++j) { eq[j] = (key[j] != 0u) && (key[j] == p); eqc += eq[j] ? 1u : 0u; }
  u32 eqtot;
  u32 eqbase = blockExScan(eqc, eqtot);
  u32 keptc = 0;
  {
    u32 er = eqbase;
#pragma unroll
    for (int j = 0; j < 4; ++j) {
      kept[j] = (key[j] != 0u) && ((key[j] > p) || (eq[j] && er < need));
      er += eq[j] ? 1u : 0u;
      keptc += kept[j] ? 1u : 0u;
    }
  }
  u32 ktot;
  u32 kbase = blockExScan(keptc, ktot);
  {
    u32 slot = kbase;
#pragma unroll
    for (int j = 0; j < 4; ++j) {
      if (kept[j]) {
        int t = tid * 4 + j;
        expert_tokens[e * CAPN + slot] = t;
        atomicOr(&keptmask[t], 1u << e);
        slot++;
      }
    }
  }
  for (u32 i = ktot + tid; i < CAPN; i += 1024) expert_tokens[e * CAPN + i] = -1;
}

// ---------- K3: rho + residual-rescale init of out ----------
__global__ __launch_bounds__(256) void rho_init_kernel(
    const float* __restrict__ h, const float* __restrict__ logits,
    const u32* __restrict__ keptmask, float* __restrict__ out)
{
  const int t = blockIdx.x;
  const int tid = threadIdx.x;
  float v[NE]; float m = -3.4e38f;
#pragma unroll
  for (int i = 0; i < NE; ++i) { v[i] = logits[(size_t)t * NE + i]; m = fmaxf(m, v[i]); }
  float sum = 0.f;
#pragma unroll
  for (int i = 0; i < NE; ++i) { v[i] = expf(v[i] - m); sum += v[i]; }
  u32 km = keptmask[t];
  float rho = 0.f;
#pragma unroll
  for (int i = 0; i < NE; ++i) if ((km >> i) & 1u) rho += v[i];
  rho /= sum;
  float s = 1.0f - rho;
  const float4 hv = *(const float4*)(h + (size_t)t * DIM + tid * 4);
  float4 o; o.x = hv.x * s; o.y = hv.y * s; o.z = hv.z * s; o.w = hv.w * s;
  *(float4*)(out + (size_t)t * DIM + tid * 4) = o;
}

// ---------- K4: transpose + f32->bf16 convert (vectorized) ----------
// out[c][r] = bf16(in[r][c]) per 1024x1024 slab. 64x64 tiles.
__global__ __launch_bounds__(256) void transpose_convert(
    const float* __restrict__ W1, const float* __restrict__ W2,
    u16* __restrict__ W1t, u16* __restrict__ W2t)
{
  const int z = blockIdx.z;
  const float* in; u16* outp;
  if (z < NE) { in = W1 + (size_t)z * DIM * NDFF;        outp = W1t + (size_t)z * DIM * NDFF; }
  else        { in = W2 + (size_t)(z - NE) * NDFF * DIM; outp = W2t + (size_t)(z - NE) * NDFF * DIM; }
  const int r0 = blockIdx.y * 64, c0 = blockIdx.x * 64;
  const int tid = threadIdx.x;
  // transposed LDS tile: lds2[col][row], row-stride 72 u16 (144 B, 16B-aligned)
  __shared__ __align__(16) u16 lds2[64 * 72];

  // Phase 1: float4 loads (wave = 4 rows x 256B, fully coalesced), convert, scatter to LDS
#pragma unroll
  for (int p = 0; p < 4; ++p) {
    const int row = (tid >> 4) + 16 * p;
    const int col = (tid & 15) * 4;
    const float4 v = *(const float4*)(in + (size_t)(r0 + row) * 1024 + c0 + col);
    lds2[(col + 0) * 72 + row] = f2bf(v.x);
    lds2[(col + 1) * 72 + row] = f2bf(v.y);
    lds2[(col + 2) * 72 + row] = f2bf(v.z);
    lds2[(col + 3) * 72 + row] = f2bf(v.w);
  }
  __syncthreads();

  // Phase 2: contiguous b128 reads of transposed rows, 16B stores (8 full lines/wave)
#pragma unroll
  for (int s = 0; s < 2; ++s) {
    const int q = tid + 256 * s;
    const int oc = q >> 3, j = q & 7;
    const uint4 d = *(const uint4*)&lds2[oc * 72 + j * 8];
    *(uint4*)(outp + (size_t)(c0 + oc) * 1024 + r0 + j * 8) = d;
  }
}

// ---------- K5: gather kept token rows -> bf16, + fused combine-weight ----------
__global__ __launch_bounds__(64) void gather_kernel(
    const float* __restrict__ h, const int* __restrict__ expert_tokens,
    const float* __restrict__ logits, u16* __restrict__ Xg, float* __restrict__ w_ec)
{
  const int slot = blockIdx.x;
  const int lane = threadIdx.x;
  const int t = expert_tokens[slot];
  u16* dst = Xg + (size_t)slot * DIM + lane * 16;
  if (t < 0) {
    if (lane == 0) w_ec[slot] = 0.f;
    uint4 z = make_uint4(0, 0, 0, 0);
    *(uint4*)dst = z; *(uint4*)(dst + 8) = z;
  } else {
    if (lane == 0) {
      const int e = slot / CAPN;
      float v[NE], m = -3.4e38f;
#pragma unroll
      for (int i = 0; i < NE; ++i) { v[i] = logits[(size_t)t * NE + i]; m = fmaxf(m, v[i]); }
      float sum = 0.f;
#pragma unroll
      for (int i = 0; i < NE; ++i) { v[i] = expf(v[i] - m); sum += v[i]; }
      w_ec[slot] = v[e] / sum;
    }
    const float4* src = (const float4*)(h + (size_t)t * DIM + lane * 16);
    __align__(16) u16 tmp[16];
#pragma unroll
    for (int q = 0; q < 4; ++q) {
      float4 x = src[q];
      tmp[q*4+0] = f2bf(x.x); tmp[q*4+1] = f2bf(x.y);
      tmp[q*4+2] = f2bf(x.z); tmp[q*4+3] = f2bf(x.w);
    }
    *(uint4*)dst = *(const uint4*)tmp;
    *(uint4*)(dst + 8) = *(const uint4*)(tmp + 8);
  }
}

// ---------- K7/K8: bf16 MFMA GEMM, A[M,K] x Bt[N,K]^T, 128x128 tile, BK=64 ----------
// EPI==1: gelu -> bf16 Hout.  EPI==2: out[token] += w * acc (atomic).
template <int EPI>
__global__ __launch_bounds__(256) void gemm_bt_kernel(
    const u16* __restrict__ Abase, const u16* __restrict__ Bbase,
    u16* __restrict__ Hout, float* __restrict__ out,
    const int* __restrict__ expert_tokens, const float* __restrict__ w_ec)
{
  const int e  = blockIdx.z;
  const int n0 = blockIdx.x * 128;
  const int m0 = blockIdx.y * 128;
  const char* A = (const char*)(Abase + (size_t)e * 512 * 1024);
  const char* B = (const char*)(Bbase + (size_t)e * 1024 * 1024);
  __shared__ __align__(16) u16 As[128 * 64];
  __shared__ __align__(16) u16 Bs[128 * 64];
  const int tid = threadIdx.x;
  const int lane = tid & 63, wave = tid >> 6;
  const int wr = wave >> 1, wc = wave & 1;
  f32x4 acc[4][4];
#pragma unroll
  for (int i = 0; i < 4; ++i)
#pragma unroll
    for (int j = 0; j < 4; ++j) acc[i][j] = (f32x4){0.f, 0.f, 0.f, 0.f};

  const int srow  = lane >> 3;                    // row within 8-row chunk
  const int sbyte = 16 * ((lane & 7) ^ srow);     // source-side XOR swizzle (rule #21)

  for (int kt = 0; kt < 16; ++kt) {
    const int kb0 = kt * 128;                     // 64 bf16 = 128 B per K-step
#pragma unroll
    for (int i = 0; i < 4; ++i) {
      const int c = wave * 4 + i;
      const int r = c * 8 + srow;
      gll16((char*)As + c * 1024, A + (size_t)(m0 + r) * 2048 + kb0 + sbyte);
      gll16((char*)Bs + c * 1024, B + (size_t)(n0 + r) * 2048 + kb0 + sbyte);
    }
    __syncthreads();
#pragma unroll
    for (int s = 0; s < 2; ++s) {
      bf16x8 af[4], bfv[4];
#pragma unroll
      for (int i = 0; i < 4; ++i) {
        const int rowa = wr * 64 + i * 16 + (lane & 15);
        const int rowb = wc * 64 + i * 16 + (lane & 15);
        const int kb = (s * 64 + (lane >> 4) * 16) ^ ((lane & 7) << 4);  // swizzled read
        af[i]  = *(const bf16x8*)((const char*)As + rowa * 128 + kb);
        bfv[i] = *(const bf16x8*)((const char*)Bs + rowb * 128 + kb);
      }
#pragma unroll
      for (int i = 0; i < 4; ++i)
#pragma unroll
        for (int j = 0; j < 4; ++j)
          acc[i][j] = __builtin_amdgcn_mfma_f32_16x16x32_bf16(af[i], bfv[j], acc[i][j], 0, 0, 0);
    }
    __syncthreads();
  }

  if (EPI == 1) {
#pragma unroll
    for (int i = 0; i < 4; ++i) {
#pragma unroll
      for (int r = 0; r < 4; ++r) {
        const int row = m0 + wr * 64 + i * 16 + (lane >> 4) * 4 + r;
        u16* hp = Hout + ((size_t)e * 512 + row) * 1024 + n0 + wc * 64 + (lane & 15);
#pragma unroll
        for (int j = 0; j < 4; ++j) hp[j * 16] = f2bf(gelu_tanh(acc[i][j][r]));
      }
    }
  } else {
#pragma unroll
    for (int i = 0; i < 4; ++i) {
#pragma unroll
      for (int r = 0; r < 4; ++r) {
        const int row  = m0 + wr * 64 + i * 16 + (lane >> 4) * 4 + r;
        const int slot = e * CAPN + row;
        const int t = expert_tokens[slot];
        if (t >= 0) {
          const float w = w_ec[slot];
          float* op = out + (size_t)t * DIM + n0 + wc * 64 + (lane & 15);
#pragma unroll
          for (int j = 0; j < 4; ++j) atomicAdd(op + j * 16, acc[i][j][r] * w);
        }
      }
    }
  }
}

// ---------- launch ----------
extern "C" void kernel_launch(void* const* d_in, const int* in_sizes, int n_in,
                              void* d_out, int out_size, void* d_ws, size_t ws_size,
                              hipStream_t stream)
{
  const float* h  = (const float*)d_in[0];
  const float* Wr = (const float*)d_in[1];
  const float* W1 = (const float*)d_in[2];
  const float* W2 = (const float*)d_in[3];
  float* out = (float*)d_out;

  char* ws = (char*)d_ws;
  u16* W1t = (u16*)(ws);                        // 33554432 B
  u16* W2t = (u16*)(ws + 33554432);             // 33554432 B
  u16* Xg  = (u16*)(ws + 67108864);             // 16777216 B
  u16* Hb  = (u16*)(ws + 83886080);             // 16777216 B
  float* logits       = (float*)(ws + 100663296); // 262144 B
  u32*   topmask      = (u32*)  (ws + 100925440); // 16384 B
  u32*   keptmask     = (u32*)  (ws + 100941824); // 16384 B
  int*   expert_tokens= (int*)  (ws + 100958208); // 32768 B
  float* w_ec         = (float*)(ws + 100990976); // 32768 B

  router_kernel<<<T_TOK, 64, 0, stream>>>(h, Wr, logits, topmask, keptmask);
  capacity_kernel<<<NE, 1024, 0, stream>>>(logits, topmask, keptmask, expert_tokens);
  rho_init_kernel<<<T_TOK, 256, 0, stream>>>(h, logits, keptmask, out);
  transpose_convert<<<dim3(16, 16, 2 * NE), dim3(256), 0, stream>>>(W1, W2, W1t, W2t);
  gather_kernel<<<NE * CAPN, 64, 0, stream>>>(h, expert_tokens, logits, Xg, w_ec);
  gemm_bt_kernel<1><<<dim3(8, 4, NE), 256, 0, stream>>>(Xg, W1t, Hb, nullptr, nullptr, nullptr);
  gemm_bt_kernel<2><<<dim3(8, 4, NE), 256, 0, stream>>>(Hb, W2t, nullptr, out, expert_tokens, w_ec);
}